// Round 1
// baseline (2340.533 us; speedup 1.0000x reference)
//
#include <hip/hip_runtime.h>

#define NS 8
#define ML 4096
#define HD 1024
#define K2 2048
#define NEV 32768
#define NLEV 12
#define NE 16384

typedef __attribute__((ext_vector_type(8))) short bf16x8;
typedef __attribute__((ext_vector_type(4))) float f32x4;

typedef __attribute__((address_space(1))) const void cvoid_g;
typedef __attribute__((address_space(3))) void void_l;

static __device__ __forceinline__ void load_lds_16(const void* g, void* l) {
    __builtin_amdgcn_global_load_lds((cvoid_g*)g, (void_l*)l, 16, 0, 0);
}

static __device__ __forceinline__ unsigned short f2bf(float f) {
    unsigned u = __float_as_uint(f);
    unsigned r = (u + 0x7fffu + ((u >> 16) & 1u)) >> 16;
    return (unsigned short)r;
}

static __device__ __forceinline__ float fast_tanh(float x) {
    // tanh(x) = 1 - 2/(exp(2x)+1); saturates correctly for |x| large
    return 1.0f - 2.0f / (__expf(2.0f * x) + 1.0f);
}

// ---- W [2048][1024] f32 -> WbT [1024][2048] bf16 (transposed) ----
__global__ void wt_kernel(const float* __restrict__ W, unsigned short* __restrict__ WbT) {
    __shared__ unsigned short tile[64][65];
    const int t = threadIdx.x;
    const int k0 = blockIdx.x * 64;   // K dim, 32 blocks
    const int n0 = blockIdx.y * 64;   // N dim, 16 blocks
#pragma unroll
    for (int i = 0; i < 16; i++) {
        int idx = i * 256 + t;
        int r = idx >> 6, c = idx & 63;
        tile[r][c] = f2bf(W[(size_t)(k0 + r) * HD + n0 + c]);
    }
    __syncthreads();
#pragma unroll
    for (int i = 0; i < 16; i++) {
        int idx = i * 256 + t;
        int r = idx >> 6, c = idx & 63;   // r: n offset, c: k offset
        WbT[(size_t)(n0 + r) * K2 + k0 + c] = tile[c][r];
    }
}

// ---- char embedding scatter-add: one block per event ----
__global__ void char_scatter(const int* __restrict__ cseq, const int* __restrict__ cpos,
                             const int* __restrict__ cid, const float* __restrict__ emb,
                             float* __restrict__ h) {
    const int e = blockIdx.x;
    const int t = threadIdx.x;
    const int seq = cseq[e], pos = cpos[e], id = cid[e];
    const float4 v = ((const float4*)(emb + (size_t)id * HD))[t];
    float* dst = h + ((size_t)seq * ML + pos) * HD + t * 4;
    atomicAdd(dst + 0, v.x);
    atomicAdd(dst + 1, v.y);
    atomicAdd(dst + 2, v.z);
    atomicAdd(dst + 3, v.w);
}

// ---- per-level gather: X[e] = bf16(concat(h[seq,first], h[seq,second])) ----
__global__ void gather_x(const float* __restrict__ h, const int* __restrict__ iseq,
                         const int* __restrict__ ifirst, const int* __restrict__ isecond,
                         unsigned short* __restrict__ X) {
    const int e = blockIdx.x;
    const int t = threadIdx.x;
    const int seq = iseq[e], f = ifirst[e], s = isecond[e];
    const float4 a = ((const float4*)(h + ((size_t)seq * ML + f) * HD))[t];
    const float4 b = ((const float4*)(h + ((size_t)seq * ML + s) * HD))[t];
    ushort4 pa, pb;
    pa.x = f2bf(a.x); pa.y = f2bf(a.y); pa.z = f2bf(a.z); pa.w = f2bf(a.w);
    pb.x = f2bf(b.x); pb.y = f2bf(b.y); pb.z = f2bf(b.z); pb.w = f2bf(b.w);
    *(ushort4*)(X + (size_t)e * K2 + t * 4) = pa;
    *(ushort4*)(X + (size_t)e * K2 + HD + t * 4) = pb;
}

// ---- fused GEMM + bias + tanh + scatter-add ----
// C[16384,1024] = tanh(X[16384,2048] @ WbT^T + b); h[seq[e],pos[e]] += C[e]
__global__ __launch_bounds__(256, 2) void gemm_scatter(
    const unsigned short* __restrict__ X,     // [NE][K2] bf16
    const unsigned short* __restrict__ WbT,   // [HD][K2] bf16 (N-major)
    const float* __restrict__ bias,           // [HD]
    const int* __restrict__ iseq, const int* __restrict__ ipos,
    float* __restrict__ h) {
    __shared__ unsigned short sA[128 * 32];
    __shared__ unsigned short sB[128 * 32];
    const int t = threadIdx.x;
    const int lane = t & 63;
    const int w = t >> 6;
    const int wm = (w >> 1) * 64, wn = (w & 1) * 64;
    const int fr = lane & 15, fq = lane >> 4;
    const int row0 = blockIdx.x * 128;   // M (events)
    const int col0 = blockIdx.y * 128;   // N (h_dim)

    f32x4 acc[4][4];
#pragma unroll
    for (int i = 0; i < 4; i++)
#pragma unroll
        for (int j = 0; j < 4; j++) acc[i][j] = (f32x4){0.f, 0.f, 0.f, 0.f};

    const unsigned short* Abase = X + (size_t)row0 * K2;
    const unsigned short* Bbase = WbT + (size_t)col0 * K2;

    for (int k0 = 0; k0 < K2; k0 += 32) {
#pragma unroll
        for (int i = 0; i < 2; i++) {
            int c = i * 256 + t;
            int r = c >> 2, p = c & 3;              // row 0..127, 16B piece 0..3
            load_lds_16(Abase + (size_t)r * K2 + k0 + p * 8, &sA[c * 8]);
            load_lds_16(Bbase + (size_t)r * K2 + k0 + p * 8, &sB[c * 8]);
        }
        __syncthreads();
        bf16x8 af[4], bfr[4];
#pragma unroll
        for (int mt = 0; mt < 4; mt++)
            af[mt] = *(const bf16x8*)&sA[(wm + mt * 16 + fr) * 32 + fq * 8];
#pragma unroll
        for (int nt = 0; nt < 4; nt++)
            bfr[nt] = *(const bf16x8*)&sB[(wn + nt * 16 + fr) * 32 + fq * 8];
#pragma unroll
        for (int mt = 0; mt < 4; mt++)
#pragma unroll
            for (int nt = 0; nt < 4; nt++)
                acc[mt][nt] = __builtin_amdgcn_mfma_f32_16x16x32_bf16(
                    af[mt], bfr[nt], acc[mt][nt], 0, 0, 0);
        __syncthreads();
    }

    // epilogue: bias + tanh + atomic scatter into h
    float bv[4];
#pragma unroll
    for (int nt = 0; nt < 4; nt++) bv[nt] = bias[col0 + wn + nt * 16 + fr];
#pragma unroll
    for (int mt = 0; mt < 4; mt++) {
#pragma unroll
        for (int r = 0; r < 4; r++) {
            const int e = row0 + wm + mt * 16 + fq * 4 + r;
            const int seq = iseq[e], pos = ipos[e];
            float* hrow = h + ((size_t)seq * ML + pos) * HD;
#pragma unroll
            for (int nt = 0; nt < 4; nt++) {
                float x = acc[mt][nt][r] + bv[nt];
                atomicAdd(&hrow[col0 + wn + nt * 16 + fr], fast_tanh(x));
            }
        }
    }
}

// ---- final: h[:, 0, :] = 0 ----
__global__ void zero_first(float* __restrict__ h) {
    const int t = blockIdx.x * 256 + threadIdx.x;  // 8192 total
    const int seq = t >> 10, d = t & 1023;
    h[(size_t)seq * ML * HD + d] = 0.0f;
}

extern "C" void kernel_launch(void* const* d_in, const int* in_sizes, int n_in,
                              void* d_out, int out_size, void* d_ws, size_t ws_size,
                              hipStream_t stream) {
    const int* char_i_seq = (const int*)d_in[0];
    const int* char_i_pos = (const int*)d_in[1];
    const int* char_ids   = (const int*)d_in[2];
    const int* grp_i_seq    = (const int*)d_in[3];   // [12][16384]
    const int* grp_i_first  = (const int*)d_in[4];
    const int* grp_i_second = (const int*)d_in[5];
    const int* grp_i_pos    = (const int*)d_in[6];
    const float* emb = (const float*)d_in[7];
    const float* W   = (const float*)d_in[8];
    const float* b   = (const float*)d_in[9];
    float* h = (float*)d_out;                         // [8][4096][1024] f32

    unsigned short* WbT = (unsigned short*)d_ws;                       // 4 MB
    unsigned short* X   = (unsigned short*)((char*)d_ws + (8 << 20));  // 64 MB

    hipMemsetAsync(h, 0, (size_t)NS * ML * HD * sizeof(float), stream);
    wt_kernel<<<dim3(32, 16), 256, 0, stream>>>(W, WbT);
    char_scatter<<<NEV, 256, 0, stream>>>(char_i_seq, char_i_pos, char_ids, emb, h);

    for (int lev = 0; lev < NLEV; lev++) {
        const int* iseq = grp_i_seq + lev * NE;
        const int* ifir = grp_i_first + lev * NE;
        const int* isec = grp_i_second + lev * NE;
        const int* ipos = grp_i_pos + lev * NE;
        gather_x<<<NE, 256, 0, stream>>>(h, iseq, ifir, isec, X);
        gemm_scatter<<<dim3(128, 8), 256, 0, stream>>>(X, WbT, b, iseq, ipos, h);
    }
    zero_first<<<32, 256, 0, stream>>>(h);
}

// Round 2
// 1954.353 us; speedup vs baseline: 1.1976x; 1.1976x over previous
//
#include <hip/hip_runtime.h>

#define NS 8
#define ML 4096
#define HD 1024
#define K2 2048
#define NEV 32768
#define NLEV 12
#define NE 16384
#define NSLOT (NS * ML)
#define CAP 8

typedef __attribute__((ext_vector_type(8))) short bf16x8;
typedef __attribute__((ext_vector_type(4))) float f32x4;

typedef __attribute__((address_space(1))) const void cvoid_g;
typedef __attribute__((address_space(3))) void void_l;

static __device__ __forceinline__ void load_lds_16(const void* g, void* l) {
    __builtin_amdgcn_global_load_lds((cvoid_g*)g, (void_l*)l, 16, 0, 0);
}

static __device__ __forceinline__ unsigned short f2bf(float f) {
    unsigned u = __float_as_uint(f);
    unsigned r = (u + 0x7fffu + ((u >> 16) & 1u)) >> 16;
    return (unsigned short)r;
}

static __device__ __forceinline__ float fast_tanh(float x) {
    return 1.0f - 2.0f / (__expf(2.0f * x) + 1.0f);
}

// ---- W [2048][1024] f32 -> WbT [1024][2048] bf16 (transposed) ----
__global__ void wt_kernel(const float* __restrict__ W, unsigned short* __restrict__ WbT) {
    __shared__ unsigned short tile[64][65];
    const int t = threadIdx.x;
    const int k0 = blockIdx.x * 64;
    const int n0 = blockIdx.y * 64;
#pragma unroll
    for (int i = 0; i < 16; i++) {
        int idx = i * 256 + t;
        int r = idx >> 6, c = idx & 63;
        tile[r][c] = f2bf(W[(size_t)(k0 + r) * HD + n0 + c]);
    }
    __syncthreads();
#pragma unroll
    for (int i = 0; i < 16; i++) {
        int idx = i * 256 + t;
        int r = idx >> 6, c = idx & 63;
        WbT[(size_t)(n0 + r) * K2 + k0 + c] = tile[c][r];
    }
}

// ---- char dedupe pass 1: ticket per event, build per-slot event list ----
__global__ void char_ticket(const int* __restrict__ cseq, const int* __restrict__ cpos,
                            int* __restrict__ counts, int* __restrict__ ticket,
                            int* __restrict__ evlist) {
    const int e = blockIdx.x * 256 + threadIdx.x;
    if (e >= NEV) return;
    const int slot = cseq[e] * ML + cpos[e];
    const int t = atomicAdd(&counts[slot], 1);
    ticket[e] = t;
    if (t < CAP) evlist[slot * CAP + t] = e;
}

// ---- char dedupe pass 2: one block per slot; sum embeddings, plain store ----
// Also zero-fills empty slots (replaces the h memset).
__global__ void char_slot_sum(const int* __restrict__ counts, const int* __restrict__ evlist,
                              const int* __restrict__ cid, const float* __restrict__ emb,
                              float* __restrict__ h) {
    const int slot = blockIdx.x;
    const int t = threadIdx.x;
    int n = counts[slot];
    if (n > CAP) n = CAP;
    float4 acc = {0.f, 0.f, 0.f, 0.f};
    for (int i = 0; i < n; i++) {
        const int e = evlist[slot * CAP + i];
        const int id = cid[e];
        const float4 v = ((const float4*)(emb + (size_t)id * HD))[t];
        acc.x += v.x; acc.y += v.y; acc.z += v.z; acc.w += v.w;
    }
    ((float4*)(h + (size_t)slot * HD))[t] = acc;
}

// ---- char overflow fallback (ticket >= CAP; astronomically rare) ----
__global__ void char_overflow(const int* __restrict__ cseq, const int* __restrict__ cpos,
                              const int* __restrict__ cid, const int* __restrict__ ticket,
                              const float* __restrict__ emb, float* __restrict__ h) {
    const int e0 = blockIdx.x * 128;
    const int t = threadIdx.x;
    for (int i = 0; i < 128; i++) {
        const int e = e0 + i;
        if (ticket[e] < CAP) continue;
        const int slot = cseq[e] * ML + cpos[e];
        const int id = cid[e];
        const float4 v = ((const float4*)(emb + (size_t)id * HD))[t];
        float* dst = h + (size_t)slot * HD + t * 4;
        atomicAdd(dst + 0, v.x);
        atomicAdd(dst + 1, v.y);
        atomicAdd(dst + 2, v.z);
        atomicAdd(dst + 3, v.w);
    }
}

// ---- per-level gather: X[e] = bf16(concat(h[seq,first], h[seq,second])) ----
__global__ void gather_x(const float* __restrict__ h, const int* __restrict__ iseq,
                         const int* __restrict__ ifirst, const int* __restrict__ isecond,
                         unsigned short* __restrict__ X) {
    const int e = blockIdx.x;
    const int t = threadIdx.x;
    const int seq = iseq[e], f = ifirst[e], s = isecond[e];
    const float4 a = ((const float4*)(h + ((size_t)seq * ML + f) * HD))[t];
    const float4 b = ((const float4*)(h + ((size_t)seq * ML + s) * HD))[t];
    ushort4 pa, pb;
    pa.x = f2bf(a.x); pa.y = f2bf(a.y); pa.z = f2bf(a.z); pa.w = f2bf(a.w);
    pb.x = f2bf(b.x); pb.y = f2bf(b.y); pb.z = f2bf(b.z); pb.w = f2bf(b.w);
    *(ushort4*)(X + (size_t)e * K2 + t * 4) = pa;
    *(ushort4*)(X + (size_t)e * K2 + HD + t * 4) = pb;
}

// ---- fused GEMM + bias + tanh + scatter-add ----
__global__ __launch_bounds__(256, 2) void gemm_scatter(
    const unsigned short* __restrict__ X,
    const unsigned short* __restrict__ WbT,
    const float* __restrict__ bias,
    const int* __restrict__ iseq, const int* __restrict__ ipos,
    float* __restrict__ h) {
    __shared__ unsigned short sA[128 * 32];
    __shared__ unsigned short sB[128 * 32];
    const int t = threadIdx.x;
    const int lane = t & 63;
    const int w = t >> 6;
    const int wm = (w >> 1) * 64, wn = (w & 1) * 64;
    const int fr = lane & 15, fq = lane >> 4;
    const int row0 = blockIdx.x * 128;
    const int col0 = blockIdx.y * 128;

    f32x4 acc[4][4];
#pragma unroll
    for (int i = 0; i < 4; i++)
#pragma unroll
        for (int j = 0; j < 4; j++) acc[i][j] = (f32x4){0.f, 0.f, 0.f, 0.f};

    const unsigned short* Abase = X + (size_t)row0 * K2;
    const unsigned short* Bbase = WbT + (size_t)col0 * K2;

    for (int k0 = 0; k0 < K2; k0 += 32) {
#pragma unroll
        for (int i = 0; i < 2; i++) {
            int c = i * 256 + t;
            int r = c >> 2, p = c & 3;
            load_lds_16(Abase + (size_t)r * K2 + k0 + p * 8, &sA[c * 8]);
            load_lds_16(Bbase + (size_t)r * K2 + k0 + p * 8, &sB[c * 8]);
        }
        __syncthreads();
        bf16x8 af[4], bfr[4];
#pragma unroll
        for (int mt = 0; mt < 4; mt++)
            af[mt] = *(const bf16x8*)&sA[(wm + mt * 16 + fr) * 32 + fq * 8];
#pragma unroll
        for (int nt = 0; nt < 4; nt++)
            bfr[nt] = *(const bf16x8*)&sB[(wn + nt * 16 + fr) * 32 + fq * 8];
#pragma unroll
        for (int mt = 0; mt < 4; mt++)
#pragma unroll
            for (int nt = 0; nt < 4; nt++)
                acc[mt][nt] = __builtin_amdgcn_mfma_f32_16x16x32_bf16(
                    af[mt], bfr[nt], acc[mt][nt], 0, 0, 0);
        __syncthreads();
    }

    float bv[4];
#pragma unroll
    for (int nt = 0; nt < 4; nt++) bv[nt] = bias[col0 + wn + nt * 16 + fr];
#pragma unroll
    for (int mt = 0; mt < 4; mt++) {
#pragma unroll
        for (int r = 0; r < 4; r++) {
            const int e = row0 + wm + mt * 16 + fq * 4 + r;
            const int seq = iseq[e], pos = ipos[e];
            float* hrow = h + ((size_t)seq * ML + pos) * HD;
#pragma unroll
            for (int nt = 0; nt < 4; nt++) {
                float x = acc[mt][nt][r] + bv[nt];
                atomicAdd(&hrow[col0 + wn + nt * 16 + fr], fast_tanh(x));
            }
        }
    }
}

// ---- final: h[:, 0, :] = 0 ----
__global__ void zero_first(float* __restrict__ h) {
    const int t = blockIdx.x * 256 + threadIdx.x;
    const int seq = t >> 10, d = t & 1023;
    h[(size_t)seq * ML * HD + d] = 0.0f;
}

extern "C" void kernel_launch(void* const* d_in, const int* in_sizes, int n_in,
                              void* d_out, int out_size, void* d_ws, size_t ws_size,
                              hipStream_t stream) {
    const int* char_i_seq = (const int*)d_in[0];
    const int* char_i_pos = (const int*)d_in[1];
    const int* char_ids   = (const int*)d_in[2];
    const int* grp_i_seq    = (const int*)d_in[3];
    const int* grp_i_first  = (const int*)d_in[4];
    const int* grp_i_second = (const int*)d_in[5];
    const int* grp_i_pos    = (const int*)d_in[6];
    const float* emb = (const float*)d_in[7];
    const float* W   = (const float*)d_in[8];
    const float* b   = (const float*)d_in[9];
    float* h = (float*)d_out;

    unsigned short* WbT = (unsigned short*)d_ws;                            // 4 MB @ 0
    unsigned short* X   = (unsigned short*)((char*)d_ws + (8 << 20));       // 64 MB @ 8M
    int* counts = (int*)((char*)d_ws + (72u << 20));                        // 128 KB
    int* ticket = (int*)((char*)d_ws + (72u << 20) + (1u << 18));           // 128 KB
    int* evlist = (int*)((char*)d_ws + (72u << 20) + (1u << 19));           // 1 MB (CAP=8)

    hipMemsetAsync(counts, 0, NSLOT * sizeof(int), stream);
    wt_kernel<<<dim3(32, 16), 256, 0, stream>>>(W, WbT);
    char_ticket<<<NEV / 256, 256, 0, stream>>>(char_i_seq, char_i_pos, counts, ticket, evlist);
    char_slot_sum<<<NSLOT, 256, 0, stream>>>(counts, evlist, char_ids, emb, h);
    char_overflow<<<NEV / 128, 256, 0, stream>>>(char_i_seq, char_i_pos, char_ids, ticket, emb, h);

    for (int lev = 0; lev < NLEV; lev++) {
        const int* iseq = grp_i_seq + lev * NE;
        const int* ifir = grp_i_first + lev * NE;
        const int* isec = grp_i_second + lev * NE;
        const int* ipos = grp_i_pos + lev * NE;
        gather_x<<<NE, 256, 0, stream>>>(h, iseq, ifir, isec, X);
        gemm_scatter<<<dim3(128, 8), 256, 0, stream>>>(X, WbT, b, iseq, ipos, h);
    }
    zero_first<<<32, 256, 0, stream>>>(h);
}

// Round 3
// 1950.524 us; speedup vs baseline: 1.2000x; 1.0020x over previous
//
#include <hip/hip_runtime.h>

#define NS 8
#define ML 4096
#define HD 1024
#define K2 2048
#define NEV 32768
#define NLEV 12
#define NE 16384
#define NSLOT (NS * ML)
#define CAP 8

typedef __attribute__((ext_vector_type(8))) short bf16x8;
typedef __attribute__((ext_vector_type(4))) float f32x4;

typedef __attribute__((address_space(1))) const void cvoid_g;
typedef __attribute__((address_space(3))) void void_l;

static __device__ __forceinline__ void load_lds_16(const void* g, void* l) {
    __builtin_amdgcn_global_load_lds((cvoid_g*)g, (void_l*)l, 16, 0, 0);
}

static __device__ __forceinline__ unsigned short f2bf(float f) {
    unsigned u = __float_as_uint(f);
    unsigned r = (u + 0x7fffu + ((u >> 16) & 1u)) >> 16;
    return (unsigned short)r;
}

static __device__ __forceinline__ float fast_tanh(float x) {
    return 1.0f - 2.0f / (__expf(2.0f * x) + 1.0f);
}

// element index of logical (row, 16B-chunk q) under xor-swizzle
static __device__ __forceinline__ int swz(int row, int q) {
    return row * 32 + ((q ^ ((row >> 1) & 3)) * 8);
}

// ---- W [2048][1024] f32 -> WbT [1024][2048] bf16 (transposed) ----
__global__ void wt_kernel(const float* __restrict__ W, unsigned short* __restrict__ WbT) {
    __shared__ unsigned short tile[64][65];
    const int t = threadIdx.x;
    const int k0 = blockIdx.x * 64;
    const int n0 = blockIdx.y * 64;
#pragma unroll
    for (int i = 0; i < 16; i++) {
        int idx = i * 256 + t;
        int r = idx >> 6, c = idx & 63;
        tile[r][c] = f2bf(W[(size_t)(k0 + r) * HD + n0 + c]);
    }
    __syncthreads();
#pragma unroll
    for (int i = 0; i < 16; i++) {
        int idx = i * 256 + t;
        int r = idx >> 6, c = idx & 63;
        WbT[(size_t)(n0 + r) * K2 + k0 + c] = tile[c][r];
    }
}

// ---- char dedupe pass 1 ----
__global__ void char_ticket(const int* __restrict__ cseq, const int* __restrict__ cpos,
                            int* __restrict__ counts, int* __restrict__ ticket,
                            int* __restrict__ evlist) {
    const int e = blockIdx.x * 256 + threadIdx.x;
    if (e >= NEV) return;
    const int slot = cseq[e] * ML + cpos[e];
    const int t = atomicAdd(&counts[slot], 1);
    ticket[e] = t;
    if (t < CAP) evlist[slot * CAP + t] = e;
}

// ---- char dedupe pass 2: plain store, zero-fills empty slots ----
__global__ void char_slot_sum(const int* __restrict__ counts, const int* __restrict__ evlist,
                              const int* __restrict__ cid, const float* __restrict__ emb,
                              float* __restrict__ h) {
    const int slot = blockIdx.x;
    const int t = threadIdx.x;
    int n = counts[slot];
    if (n > CAP) n = CAP;
    float4 acc = {0.f, 0.f, 0.f, 0.f};
    for (int i = 0; i < n; i++) {
        const int e = evlist[slot * CAP + i];
        const int id = cid[e];
        const float4 v = ((const float4*)(emb + (size_t)id * HD))[t];
        acc.x += v.x; acc.y += v.y; acc.z += v.z; acc.w += v.w;
    }
    ((float4*)(h + (size_t)slot * HD))[t] = acc;
}

// ---- char overflow fallback ----
__global__ void char_overflow(const int* __restrict__ cseq, const int* __restrict__ cpos,
                              const int* __restrict__ cid, const int* __restrict__ ticket,
                              const float* __restrict__ emb, float* __restrict__ h) {
    const int e0 = blockIdx.x * 128;
    const int t = threadIdx.x;
    for (int i = 0; i < 128; i++) {
        const int e = e0 + i;
        if (ticket[e] < CAP) continue;
        const int slot = cseq[e] * ML + cpos[e];
        const int id = cid[e];
        const float4 v = ((const float4*)(emb + (size_t)id * HD))[t];
        float* dst = h + (size_t)slot * HD + t * 4;
        atomicAdd(dst + 0, v.x);
        atomicAdd(dst + 1, v.y);
        atomicAdd(dst + 2, v.z);
        atomicAdd(dst + 3, v.w);
    }
}

// ---- per-level gather ----
__global__ void gather_x(const float* __restrict__ h, const int* __restrict__ iseq,
                         const int* __restrict__ ifirst, const int* __restrict__ isecond,
                         unsigned short* __restrict__ X) {
    const int e = blockIdx.x;
    const int t = threadIdx.x;
    const int seq = iseq[e], f = ifirst[e], s = isecond[e];
    const float4 a = ((const float4*)(h + ((size_t)seq * ML + f) * HD))[t];
    const float4 b = ((const float4*)(h + ((size_t)seq * ML + s) * HD))[t];
    ushort4 pa, pb;
    pa.x = f2bf(a.x); pa.y = f2bf(a.y); pa.z = f2bf(a.z); pa.w = f2bf(a.w);
    pb.x = f2bf(b.x); pb.y = f2bf(b.y); pb.z = f2bf(b.z); pb.w = f2bf(b.w);
    *(ushort4*)(X + (size_t)e * K2 + t * 4) = pa;
    *(ushort4*)(X + (size_t)e * K2 + HD + t * 4) = pb;
}

// ---- fused GEMM + bias + tanh + scatter-add, xor-swizzled LDS ----
__global__ __launch_bounds__(256, 4) void gemm_scatter(
    const unsigned short* __restrict__ X,
    const unsigned short* __restrict__ WbT,
    const float* __restrict__ bias,
    const int* __restrict__ iseq, const int* __restrict__ ipos,
    float* __restrict__ h) {
    __shared__ unsigned short sA[128 * 32];
    __shared__ unsigned short sB[128 * 32];
    const int t = threadIdx.x;
    const int lane = t & 63;
    const int w = t >> 6;
    const int wm = (w >> 1) * 64, wn = (w & 1) * 64;
    const int fr = lane & 15, fq = lane >> 4;
    const int row0 = blockIdx.x * 128;
    const int col0 = blockIdx.y * 128;

    f32x4 acc[4][4];
#pragma unroll
    for (int i = 0; i < 4; i++)
#pragma unroll
        for (int j = 0; j < 4; j++) acc[i][j] = (f32x4){0.f, 0.f, 0.f, 0.f};

    const unsigned short* Abase = X + (size_t)row0 * K2;
    const unsigned short* Bbase = WbT + (size_t)col0 * K2;

    // precompute swizzled staging source (which global 16B chunk feeds this
    // thread's contiguous LDS chunk) and swizzled read offsets
    int stage_r[2], stage_p[2];
#pragma unroll
    for (int i = 0; i < 2; i++) {
        int c = i * 256 + t;
        int r = c >> 2, pos = c & 3;
        stage_r[i] = r;
        stage_p[i] = pos ^ ((r >> 1) & 3);
    }

    for (int k0 = 0; k0 < K2; k0 += 32) {
#pragma unroll
        for (int i = 0; i < 2; i++) {
            int c = i * 256 + t;
            int r = stage_r[i], p = stage_p[i];
            load_lds_16(Abase + (size_t)r * K2 + k0 + p * 8, &sA[c * 8]);
            load_lds_16(Bbase + (size_t)r * K2 + k0 + p * 8, &sB[c * 8]);
        }
        __syncthreads();
        bf16x8 af[4], bfr[4];
#pragma unroll
        for (int mt = 0; mt < 4; mt++)
            af[mt] = *(const bf16x8*)&sA[swz(wm + mt * 16 + fr, fq)];
#pragma unroll
        for (int nt = 0; nt < 4; nt++)
            bfr[nt] = *(const bf16x8*)&sB[swz(wn + nt * 16 + fr, fq)];
#pragma unroll
        for (int mt = 0; mt < 4; mt++)
#pragma unroll
            for (int nt = 0; nt < 4; nt++)
                acc[mt][nt] = __builtin_amdgcn_mfma_f32_16x16x32_bf16(
                    af[mt], bfr[nt], acc[mt][nt], 0, 0, 0);
        __syncthreads();
    }

    float bv[4];
#pragma unroll
    for (int nt = 0; nt < 4; nt++) bv[nt] = bias[col0 + wn + nt * 16 + fr];
#pragma unroll
    for (int mt = 0; mt < 4; mt++) {
#pragma unroll
        for (int r = 0; r < 4; r++) {
            const int e = row0 + wm + mt * 16 + fq * 4 + r;
            const int seq = iseq[e], pos = ipos[e];
            float* hrow = h + ((size_t)seq * ML + pos) * HD;
#pragma unroll
            for (int nt = 0; nt < 4; nt++) {
                float x = acc[mt][nt][r] + bv[nt];
                atomicAdd(&hrow[col0 + wn + nt * 16 + fr], fast_tanh(x));
            }
        }
    }
}

// ---- final: h[:, 0, :] = 0 ----
__global__ void zero_first(float* __restrict__ h) {
    const int t = blockIdx.x * 256 + threadIdx.x;
    const int seq = t >> 10, d = t & 1023;
    h[(size_t)seq * ML * HD + d] = 0.0f;
}

extern "C" void kernel_launch(void* const* d_in, const int* in_sizes, int n_in,
                              void* d_out, int out_size, void* d_ws, size_t ws_size,
                              hipStream_t stream) {
    const int* char_i_seq = (const int*)d_in[0];
    const int* char_i_pos = (const int*)d_in[1];
    const int* char_ids   = (const int*)d_in[2];
    const int* grp_i_seq    = (const int*)d_in[3];
    const int* grp_i_first  = (const int*)d_in[4];
    const int* grp_i_second = (const int*)d_in[5];
    const int* grp_i_pos    = (const int*)d_in[6];
    const float* emb = (const float*)d_in[7];
    const float* W   = (const float*)d_in[8];
    const float* b   = (const float*)d_in[9];
    float* h = (float*)d_out;

    unsigned short* WbT = (unsigned short*)d_ws;                            // 4 MB @ 0
    unsigned short* X   = (unsigned short*)((char*)d_ws + (8 << 20));       // 64 MB @ 8M
    int* counts = (int*)((char*)d_ws + (72u << 20));                        // 128 KB
    int* ticket = (int*)((char*)d_ws + (72u << 20) + (1u << 18));           // 128 KB
    int* evlist = (int*)((char*)d_ws + (72u << 20) + (1u << 19));           // 1 MB

    hipMemsetAsync(counts, 0, NSLOT * sizeof(int), stream);
    wt_kernel<<<dim3(32, 16), 256, 0, stream>>>(W, WbT);
    char_ticket<<<NEV / 256, 256, 0, stream>>>(char_i_seq, char_i_pos, counts, ticket, evlist);
    char_slot_sum<<<NSLOT, 256, 0, stream>>>(counts, evlist, char_ids, emb, h);
    char_overflow<<<NEV / 128, 256, 0, stream>>>(char_i_seq, char_i_pos, char_ids, ticket, emb, h);

    for (int lev = 0; lev < NLEV; lev++) {
        const int* iseq = grp_i_seq + lev * NE;
        const int* ifir = grp_i_first + lev * NE;
        const int* isec = grp_i_second + lev * NE;
        const int* ipos = grp_i_pos + lev * NE;
        gather_x<<<NE, 256, 0, stream>>>(h, iseq, ifir, isec, X);
        gemm_scatter<<<dim3(128, 8), 256, 0, stream>>>(X, WbT, b, iseq, ipos, h);
    }
    zero_first<<<32, 256, 0, stream>>>(h);
}

// Round 4
// 1722.284 us; speedup vs baseline: 1.3590x; 1.1325x over previous
//
#include <hip/hip_runtime.h>

#define NS 8
#define ML 4096
#define HD 1024
#define K2 2048
#define NEV 32768
#define NLEV 12
#define NE 16384
#define NSLOT (NS * ML)
#define CAP 8
#define BK 64

typedef __attribute__((ext_vector_type(8))) short bf16x8;
typedef __attribute__((ext_vector_type(4))) float f32x4;

typedef __attribute__((address_space(1))) const void cvoid_g;
typedef __attribute__((address_space(3))) void void_l;

static __device__ __forceinline__ void load_lds_16(const void* g, void* l) {
    __builtin_amdgcn_global_load_lds((cvoid_g*)g, (void_l*)l, 16, 0, 0);
}

static __device__ __forceinline__ unsigned short f2bf(float f) {
    unsigned u = __float_as_uint(f);
    unsigned r = (u + 0x7fffu + ((u >> 16) & 1u)) >> 16;
    return (unsigned short)r;
}

static __device__ __forceinline__ float fast_tanh(float x) {
    return 1.0f - 2.0f / (__expf(2.0f * x) + 1.0f);
}

// ---- W [2048][1024] f32 -> WbT [1024][2048] bf16 (transposed) ----
__global__ void wt_kernel(const float* __restrict__ W, unsigned short* __restrict__ WbT) {
    __shared__ unsigned short tile[64][65];
    const int t = threadIdx.x;
    const int k0 = blockIdx.x * 64;
    const int n0 = blockIdx.y * 64;
#pragma unroll
    for (int i = 0; i < 16; i++) {
        int idx = i * 256 + t;
        int r = idx >> 6, c = idx & 63;
        tile[r][c] = f2bf(W[(size_t)(k0 + r) * HD + n0 + c]);
    }
    __syncthreads();
#pragma unroll
    for (int i = 0; i < 16; i++) {
        int idx = i * 256 + t;
        int r = idx >> 6, c = idx & 63;
        WbT[(size_t)(n0 + r) * K2 + k0 + c] = tile[c][r];
    }
}

// ---- char dedupe pass 1 ----
__global__ void char_ticket(const int* __restrict__ cseq, const int* __restrict__ cpos,
                            int* __restrict__ counts, int* __restrict__ ticket,
                            int* __restrict__ evlist) {
    const int e = blockIdx.x * 256 + threadIdx.x;
    if (e >= NEV) return;
    const int slot = cseq[e] * ML + cpos[e];
    const int t = atomicAdd(&counts[slot], 1);
    ticket[e] = t;
    if (t < CAP) evlist[slot * CAP + t] = e;
}

// ---- char dedupe pass 2: plain store, zero-fills empty slots ----
__global__ void char_slot_sum(const int* __restrict__ counts, const int* __restrict__ evlist,
                              const int* __restrict__ cid, const float* __restrict__ emb,
                              float* __restrict__ h) {
    const int slot = blockIdx.x;
    const int t = threadIdx.x;
    int n = counts[slot];
    if (n > CAP) n = CAP;
    float4 acc = {0.f, 0.f, 0.f, 0.f};
    for (int i = 0; i < n; i++) {
        const int e = evlist[slot * CAP + i];
        const int id = cid[e];
        const float4 v = ((const float4*)(emb + (size_t)id * HD))[t];
        acc.x += v.x; acc.y += v.y; acc.z += v.z; acc.w += v.w;
    }
    ((float4*)(h + (size_t)slot * HD))[t] = acc;
}

// ---- char overflow fallback ----
__global__ void char_overflow(const int* __restrict__ cseq, const int* __restrict__ cpos,
                              const int* __restrict__ cid, const int* __restrict__ ticket,
                              const float* __restrict__ emb, float* __restrict__ h) {
    const int e0 = blockIdx.x * 128;
    const int t = threadIdx.x;
    for (int i = 0; i < 128; i++) {
        const int e = e0 + i;
        if (ticket[e] < CAP) continue;
        const int slot = cseq[e] * ML + cpos[e];
        const int id = cid[e];
        const float4 v = ((const float4*)(emb + (size_t)id * HD))[t];
        float* dst = h + (size_t)slot * HD + t * 4;
        atomicAdd(dst + 0, v.x);
        atomicAdd(dst + 1, v.y);
        atomicAdd(dst + 2, v.z);
        atomicAdd(dst + 3, v.w);
    }
}

// ---- group-event dup detection (all 12 levels at once; indices are static) ----
__global__ void grp_count(const int* __restrict__ iseq, const int* __restrict__ ipos,
                          int* __restrict__ gcounts) {
    const int idx = blockIdx.x * 256 + threadIdx.x;   // 12*16384
    if (idx >= NLEV * NE) return;
    const int lev = idx >> 14;
    atomicAdd(&gcounts[lev * NSLOT + iseq[idx] * ML + ipos[idx]], 1);
}

__global__ void grp_dup(const int* __restrict__ iseq, const int* __restrict__ ipos,
                        const int* __restrict__ gcounts, unsigned char* __restrict__ dup) {
    const int idx = blockIdx.x * 256 + threadIdx.x;
    if (idx >= NLEV * NE) return;
    const int lev = idx >> 14;
    dup[idx] = (gcounts[lev * NSLOT + iseq[idx] * ML + ipos[idx]] > 1) ? 1 : 0;
}

// ---- per-level gather ----
__global__ void gather_x(const float* __restrict__ h, const int* __restrict__ iseq,
                         const int* __restrict__ ifirst, const int* __restrict__ isecond,
                         unsigned short* __restrict__ X) {
    const int e = blockIdx.x;
    const int t = threadIdx.x;
    const int seq = iseq[e], f = ifirst[e], s = isecond[e];
    const float4 a = ((const float4*)(h + ((size_t)seq * ML + f) * HD))[t];
    const float4 b = ((const float4*)(h + ((size_t)seq * ML + s) * HD))[t];
    ushort4 pa, pb;
    pa.x = f2bf(a.x); pa.y = f2bf(a.y); pa.z = f2bf(a.z); pa.w = f2bf(a.w);
    pb.x = f2bf(b.x); pb.y = f2bf(b.y); pb.z = f2bf(b.z); pb.w = f2bf(b.w);
    *(ushort4*)(X + (size_t)e * K2 + t * 4) = pa;
    *(ushort4*)(X + (size_t)e * K2 + HD + t * 4) = pb;
}

// ---- fused GEMM + bias + tanh + dedupe'd scatter, BK=64, xor-swizzled LDS ----
__global__ __launch_bounds__(256, 3) void gemm_scatter(
    const unsigned short* __restrict__ X,
    const unsigned short* __restrict__ WbT,
    const float* __restrict__ bias,
    const int* __restrict__ iseq, const int* __restrict__ ipos,
    const unsigned char* __restrict__ dup,
    float* __restrict__ h) {
    __shared__ unsigned short sA[128 * BK];
    __shared__ unsigned short sB[128 * BK];
    const int t = threadIdx.x;
    const int lane = t & 63;
    const int w = t >> 6;
    const int wm = (w >> 1) * 64, wn = (w & 1) * 64;
    const int fr = lane & 15, fq = lane >> 4;
    const int row0 = blockIdx.x * 128;
    const int col0 = blockIdx.y * 128;

    f32x4 acc[4][4];
#pragma unroll
    for (int i = 0; i < 4; i++)
#pragma unroll
        for (int j = 0; j < 4; j++) acc[i][j] = (f32x4){0.f, 0.f, 0.f, 0.f};

    // staging geometry: 1024 chunks of 16B per matrix; thread t handles physical
    // chunks c = i*256+t (i=0..3); row r = c>>3, phys pos pp = c&7,
    // global src pos p = pp ^ (r&7)  (xor-swizzle; self-inverse)
    const int sr = t >> 3;                       // row within 32-row group
    const int sp = (t & 7) ^ (sr & 7);           // swizzled 16B-chunk source
    const unsigned short* Asrc = X + (size_t)(row0 + sr) * K2 + sp * 8;
    const unsigned short* Bsrc = WbT + (size_t)(col0 + sr) * K2 + sp * 8;

    // swizzled read offsets (element index): row*BK + (q ^ (fr&7))*8
    const int s7 = fr & 7;

    for (int k0 = 0; k0 < K2; k0 += BK) {
#pragma unroll
        for (int i = 0; i < 4; i++) {
            const int c = i * 256 + t;
            load_lds_16(Asrc + (size_t)i * 32 * K2 + k0, &sA[c * 8]);
            load_lds_16(Bsrc + (size_t)i * 32 * K2 + k0, &sB[c * 8]);
        }
        __syncthreads();
#pragma unroll
        for (int pass = 0; pass < 2; pass++) {
            const int q = pass * 4 + fq;
            const int qs = (q ^ s7) * 8;
            bf16x8 af[4], bfr[4];
#pragma unroll
            for (int mt = 0; mt < 4; mt++)
                af[mt] = *(const bf16x8*)&sA[(wm + mt * 16 + fr) * BK + qs];
#pragma unroll
            for (int nt = 0; nt < 4; nt++)
                bfr[nt] = *(const bf16x8*)&sB[(wn + nt * 16 + fr) * BK + qs];
#pragma unroll
            for (int mt = 0; mt < 4; mt++)
#pragma unroll
                for (int nt = 0; nt < 4; nt++)
                    acc[mt][nt] = __builtin_amdgcn_mfma_f32_16x16x32_bf16(
                        af[mt], bfr[nt], acc[mt][nt], 0, 0, 0);
        }
        __syncthreads();
    }

    // epilogue: bias + tanh; sole-writer events use plain RMW, dups use atomics
    float bv[4];
#pragma unroll
    for (int nt = 0; nt < 4; nt++) bv[nt] = bias[col0 + wn + nt * 16 + fr];
#pragma unroll
    for (int mt = 0; mt < 4; mt++) {
#pragma unroll
        for (int r = 0; r < 4; r++) {
            const int e = row0 + wm + mt * 16 + fq * 4 + r;
            const int seq = iseq[e], pos = ipos[e];
            float* hrow = h + ((size_t)seq * ML + pos) * HD + col0 + wn;
            const bool d = dup[e] != 0;
            if (d) {
#pragma unroll
                for (int nt = 0; nt < 4; nt++) {
                    float x = fast_tanh(acc[mt][nt][r] + bv[nt]);
                    atomicAdd(&hrow[nt * 16 + fr], x);
                }
            } else {
#pragma unroll
                for (int nt = 0; nt < 4; nt++) {
                    float x = fast_tanh(acc[mt][nt][r] + bv[nt]);
                    hrow[nt * 16 + fr] += x;
                }
            }
        }
    }
}

// ---- final: h[:, 0, :] = 0 ----
__global__ void zero_first(float* __restrict__ h) {
    const int t = blockIdx.x * 256 + threadIdx.x;
    const int seq = t >> 10, d = t & 1023;
    h[(size_t)seq * ML * HD + d] = 0.0f;
}

extern "C" void kernel_launch(void* const* d_in, const int* in_sizes, int n_in,
                              void* d_out, int out_size, void* d_ws, size_t ws_size,
                              hipStream_t stream) {
    const int* char_i_seq = (const int*)d_in[0];
    const int* char_i_pos = (const int*)d_in[1];
    const int* char_ids   = (const int*)d_in[2];
    const int* grp_i_seq    = (const int*)d_in[3];
    const int* grp_i_first  = (const int*)d_in[4];
    const int* grp_i_second = (const int*)d_in[5];
    const int* grp_i_pos    = (const int*)d_in[6];
    const float* emb = (const float*)d_in[7];
    const float* W   = (const float*)d_in[8];
    const float* b   = (const float*)d_in[9];
    float* h = (float*)d_out;

    unsigned short* WbT = (unsigned short*)d_ws;                            // 4 MB @ 0
    unsigned short* X   = (unsigned short*)((char*)d_ws + (8u << 20));      // 64 MB @ 8M
    int* counts = (int*)((char*)d_ws + (72u << 20));                        // 128 KB
    int* ticket = (int*)((char*)d_ws + (72u << 20) + (1u << 18));           // 128 KB
    int* evlist = (int*)((char*)d_ws + (72u << 20) + (1u << 19));           // 1 MB
    int* gcounts = (int*)((char*)d_ws + (74u << 20));                       // 1.5 MB
    unsigned char* gdup = (unsigned char*)((char*)d_ws + (76u << 20));      // 192 KB

    hipMemsetAsync(counts, 0, NSLOT * sizeof(int), stream);
    hipMemsetAsync(gcounts, 0, (size_t)NLEV * NSLOT * sizeof(int), stream);
    wt_kernel<<<dim3(32, 16), 256, 0, stream>>>(W, WbT);
    char_ticket<<<NEV / 256, 256, 0, stream>>>(char_i_seq, char_i_pos, counts, ticket, evlist);
    char_slot_sum<<<NSLOT, 256, 0, stream>>>(counts, evlist, char_ids, emb, h);
    char_overflow<<<NEV / 128, 256, 0, stream>>>(char_i_seq, char_i_pos, char_ids, ticket, emb, h);
    grp_count<<<(NLEV * NE) / 256, 256, 0, stream>>>(grp_i_seq, grp_i_pos, gcounts);
    grp_dup<<<(NLEV * NE) / 256, 256, 0, stream>>>(grp_i_seq, grp_i_pos, gcounts, gdup);

    for (int lev = 0; lev < NLEV; lev++) {
        const int* iseq = grp_i_seq + lev * NE;
        const int* ifir = grp_i_first + lev * NE;
        const int* isec = grp_i_second + lev * NE;
        const int* ipos = grp_i_pos + lev * NE;
        gather_x<<<NE, 256, 0, stream>>>(h, iseq, ifir, isec, X);
        gemm_scatter<<<dim3(128, 8), 256, 0, stream>>>(X, WbT, b, iseq, ipos,
                                                       gdup + lev * NE, h);
    }
    zero_first<<<32, 256, 0, stream>>>(h);
}